// Round 1
// baseline (161.710 us; speedup 1.0000x reference)
//
#include <hip/hip_runtime.h>

typedef unsigned short u16;
typedef __attribute__((ext_vector_type(8))) short short8;
typedef __attribute__((ext_vector_type(4))) float float4v;

#define D_DIM 128
#define M_DIM 128
#define BQ 4096
#define BK 8192

// round-to-nearest-even fp32 -> bf16 (no NaN handling needed; inputs are finite)
static __device__ inline u16 f2bf(float f) {
    unsigned int x = __float_as_uint(f);
    unsigned int r = (x + 0x7FFFu + ((x >> 16) & 1u)) >> 16;
    return (u16)r;
}

// ---------------------------------------------------------------------------
// Projection kernel: X (rows x 128) @ S^T (128x128) in fp32.
// SIGNS=true : emit bf16 sign(+1/-1) and normscale[row] = ||x|| * sqrt(pi/2)/128
// SIGNS=false: emit bf16 round of the projection (query path)
// 16 rows per block, 256 threads: thread t -> column m = t&127, group g = t>>7
// handles 8 rows. Rows staged in LDS (wave-uniform broadcast reads).
// ---------------------------------------------------------------------------
template <bool SIGNS>
__global__ __launch_bounds__(256) void proj_kernel(
    const float* __restrict__ X, const float* __restrict__ S,
    u16* __restrict__ out, float* __restrict__ normscale)
{
    __shared__ float rows[16 * 128];  // 8 KB
    const int tid = threadIdx.x;
    const int blk = blockIdx.x;

    // stage 16 rows (2048 floats) contiguously
    const float4v* xs = (const float4v*)(X + (size_t)blk * 16 * 128);
    float4v* ls = (float4v*)rows;
    ls[tid]       = xs[tid];
    ls[tid + 256] = xs[tid + 256];
    __syncthreads();

    const int m = tid & 127;
    const int g = tid >> 7;           // wave-uniform (waves 0,1 -> 0; 2,3 -> 1)

    float acc[8] = {0.f, 0.f, 0.f, 0.f, 0.f, 0.f, 0.f, 0.f};
    const float4v* S4 = (const float4v*)S;

    #pragma unroll 4
    for (int k4 = 0; k4 < 32; ++k4) {
        float4v s = S4[m * 32 + k4];
        #pragma unroll
        for (int rr = 0; rr < 8; ++rr) {
            float4v x = *(const float4v*)&rows[(g * 8 + rr) * 128 + k4 * 4];
            acc[rr] += s.x * x.x;
            acc[rr] += s.y * x.y;
            acc[rr] += s.z * x.z;
            acc[rr] += s.w * x.w;
        }
    }

    #pragma unroll
    for (int rr = 0; rr < 8; ++rr) {
        int row = blk * 16 + g * 8 + rr;
        u16 v;
        if (SIGNS) {
            v = (acc[rr] >= 0.f) ? (u16)0x3F80u : (u16)0xBF80u;
        } else {
            v = f2bf(acc[rr]);
        }
        out[(size_t)row * 128 + m] = v;
    }

    if (SIGNS) {
        // fused norms: 16 threads per row, each sums 8 squares from LDS
        const int r16 = tid >> 4;     // row 0..15
        const int seg = tid & 15;
        float p = 0.f;
        #pragma unroll
        for (int e = 0; e < 8; ++e) {
            float v = rows[r16 * 128 + seg * 8 + e];
            p += v * v;
        }
        p += __shfl_xor(p, 1);
        p += __shfl_xor(p, 2);
        p += __shfl_xor(p, 4);
        p += __shfl_xor(p, 8);
        if (seg == 0) {
            const float scale = 1.2533141373155003f / 128.0f;  // sqrt(pi/2)/m
            normscale[blk * 16 + r16] = sqrtf(p) * scale;
        }
    }
}

// ---------------------------------------------------------------------------
// Main GEMM: out[i][j] = ns[j] * sum_k qp[i][k] * sg[j][k]
// qp: BQ x 128 bf16, sg: BK x 128 bf16 (both row-major, k contiguous)
// 128x128 tile per block, 4 waves in 2x2, each wave 64x64 via 4x4 frags of
// mfma_f32_16x16x32_bf16. K=128 staged once into LDS (row stride 136 to
// break the 16-way bank conflict on ds_read_b128 frag loads).
// ---------------------------------------------------------------------------
__global__ __launch_bounds__(256) void qjl_gemm(
    const u16* __restrict__ qp, const u16* __restrict__ sg,
    const float* __restrict__ ns, float* __restrict__ out)
{
    __shared__ u16 Asm[128 * 136];
    __shared__ u16 Bsm[128 * 136];

    const int tid = threadIdx.x;
    const int j0 = blockIdx.x * 128;  // key tile
    const int i0 = blockIdx.y * 128;  // query tile

    // stage A (qp tile) and B (signs tile): each is a contiguous 32 KB slab
    const uint4* As = (const uint4*)(qp + (size_t)i0 * 128);
    const uint4* Bs = (const uint4*)(sg + (size_t)j0 * 128);
    #pragma unroll
    for (int i = 0; i < 8; ++i) {
        int c = tid + i * 256;          // 16B chunk id, 2048 per tile
        int row = c >> 4;
        int col8 = (c & 15) << 3;       // element col
        *(uint4*)&Asm[row * 136 + col8] = As[c];
        *(uint4*)&Bsm[row * 136 + col8] = Bs[c];
    }
    __syncthreads();

    const int lane = tid & 63;
    const int wid = tid >> 6;
    const int q = lane >> 4;            // quad 0..3
    const int r16 = lane & 15;
    const int wrow = (wid & 1) * 64;
    const int wcol = (wid >> 1) * 64;

    float4v acc[4][4] = {};

    #pragma unroll
    for (int kk = 0; kk < 4; ++kk) {    // K steps of 32
        short8 a[4], b[4];
        #pragma unroll
        for (int t = 0; t < 4; ++t) {
            a[t] = *(const short8*)&Asm[(wrow + t * 16 + r16) * 136 + kk * 32 + q * 8];
            b[t] = *(const short8*)&Bsm[(wcol + t * 16 + r16) * 136 + kk * 32 + q * 8];
        }
        #pragma unroll
        for (int it = 0; it < 4; ++it)
            #pragma unroll
            for (int jt = 0; jt < 4; ++jt)
                acc[it][jt] = __builtin_amdgcn_mfma_f32_16x16x32_bf16(
                    a[it], b[jt], acc[it][jt], 0, 0, 0);
    }

    // epilogue: scale by normscale[col]; C/D layout col=lane&15, row=q*4+reg
    #pragma unroll
    for (int jt = 0; jt < 4; ++jt) {
        const int col = j0 + wcol + jt * 16 + r16;
        const float nsv = ns[col];
        #pragma unroll
        for (int it = 0; it < 4; ++it) {
            const int rbase = i0 + wrow + it * 16 + q * 4;
            #pragma unroll
            for (int rg = 0; rg < 4; ++rg) {
                out[(size_t)(rbase + rg) * BK + col] = acc[it][jt][rg] * nsv;
            }
        }
    }
}

extern "C" void kernel_launch(void* const* d_in, const int* in_sizes, int n_in,
                              void* d_out, int out_size, void* d_ws, size_t ws_size,
                              hipStream_t stream) {
    const float* query    = (const float*)d_in[0];  // (4096, 128)
    const float* residual = (const float*)d_in[1];  // (8192, 128)
    const float* S        = (const float*)d_in[2];  // (128, 128)
    float* out = (float*)d_out;                     // (4096, 8192)

    char* ws = (char*)d_ws;
    u16*   qp = (u16*)ws;                       // 4096*128*2 = 1 MB
    u16*   sg = (u16*)(ws + (1u << 20));        // 8192*128*2 = 2 MB
    float* ns = (float*)(ws + (3u << 20));      // 8192*4     = 32 KB

    // query projection -> bf16 qp
    proj_kernel<false><<<dim3(BQ / 16), 256, 0, stream>>>(query, S, qp, nullptr);
    // residual projection -> bf16 signs + normscale
    proj_kernel<true><<<dim3(BK / 16), 256, 0, stream>>>(residual, S, sg, ns);
    // main GEMM + epilogue scale
    qjl_gemm<<<dim3(BK / 128, BQ / 128), 256, 0, stream>>>(qp, sg, ns, out);
}